// Round 5
// baseline (176.732 us; speedup 1.0000x reference)
//
#include <hip/hip_runtime.h>
#include <math.h>

// DAS beamforming: out[b][c][p] = sum_s data[b][c][s][t(s,p)]
// t(s,p) depends only on (|x_s - ix|, |y_s - iy|) -> precompute 512x512 u16 table.
//
// Table-chain evidence so far (absmax vs harness 'np' ref):
//   r1/r2 faithful f32, two CR divides:        5.6875  (bit-identical twice)
//   r3    pure f64 chain:                      5.5636
//   r4    f32, folded single divide:           5.5636
// => reference = jax.jit/XLA. Post-order algebraic simplification rewrites each
// divide-by-constant as multiply-by-folded-reciprocal (inner div first, so the
// A/B/C->A/(B*C) fold never fires):
//   r1c = f32(1/1550.0f)            (CR f32 reciprocal)
//   r2c = f32(1/f32(2.5e-8f)) = 4.0e7 exactly (78125*2^9, f32-representable)
//   q   = f32( f32(dis * r1c) * r2c ),  dis = per-op f32 chain, trunc -> t
// All f32 ops emulated via f64 + single f32 round (exact & compile-flag-proof):
//   int*DX32 (33-bit), dx*dx (48-bit), a2+b2, f32*f32 products: exact in f64.
//   sqrt / reciprocal fold: CR f64 then f32 round == CR f32 (Figueroa, 53>=2*24+2).
// max t = 1864 < 2048, no clamp needed.

#define NXY 512
#define S_CNT 128
#define T_CNT 2048
#define CH 8                       // B*2 = 4*2
#define CH_STRIDE (S_CNT * T_CNT)  // 262144 floats between channels
#define NPIX (NXY * NXY)

#pragma float_control(push)
#pragma float_control(precise, on)
__global__ __launch_bounds__(256) void build_table(unsigned short* __restrict__ tab) {
    int idx = blockIdx.x * 256 + threadIdx.x;  // 0 .. 262143
    int adx = idx >> 9;                        // |dx| 0..511
    int ady = idx & 511;                       // |dy| 0..511

    const double DX32 = (double)1e-4f;              // f32 constant, widened exactly
    const double R1 = (double)(float)(1.0 / 1550.0);            // CR f32 recip (Figueroa)
    const double R2 = (double)(float)(1.0 / (double)2.5e-8f);   // = 4.0e7 exactly

    float dxf = (float)((double)adx * DX32);        // exact f64 product -> f32 round
    float dyf = (float)((double)ady * DX32);
    float a2 = (float)((double)dxf * (double)dxf);  // exact in f64 -> f32 round
    float b2 = (float)((double)dyf * (double)dyf);
    float sum = (float)((double)a2 + (double)b2);   // exact in f64 -> f32 round
    float dis = (float)sqrt((double)sum);           // CR f32 sqrt via Figueroa
    float q1 = (float)((double)dis * R1);           // CR f32 mul (exact f64 product)
    float q2 = (float)((double)q1 * R2);            // CR f32 mul (exact f64 product)
    tab[idx] = (unsigned short)(int)q2;             // trunc toward zero = convert<s32>
}
#pragma float_control(pop)

__global__ __launch_bounds__(256) void das_main(const float* __restrict__ data,
                                                const unsigned short* __restrict__ tab,
                                                const int* __restrict__ sxy,
                                                float* __restrict__ out) {
    __shared__ int sx[S_CNT];
    __shared__ int sy[S_CNT];
    int tid = threadIdx.x;
    if (tid < S_CNT) {
        sx[tid] = sxy[2 * tid];
        sy[tid] = sxy[2 * tid + 1];
    }
    __syncthreads();

    // Block = 16x16 pixel tile; wave = 16(iy) x 4(ix) -> small t-spread per gather.
    int iy = ((blockIdx.x & 31) << 4) | (tid & 15);
    int ix = ((blockIdx.x >> 5) << 4) | (tid >> 4);

    float acc[CH];
#pragma unroll
    for (int k = 0; k < CH; ++k) acc[k] = 0.0f;

#pragma unroll 4
    for (int s = 0; s < S_CNT; ++s) {
        int dxi = sx[s] - ix;
        int dyi = sy[s] - iy;
        int adx = dxi < 0 ? -dxi : dxi;
        int ady = dyi < 0 ? -dyi : dyi;
        int t = (int)tab[(adx << 9) | ady];
        const float* p = data + (s << 11) + t;
#pragma unroll
        for (int k = 0; k < CH; ++k) {
            acc[k] += p[(size_t)k * CH_STRIDE];  // s-ascending adds per channel
        }
    }

    int pix = (ix << 9) | iy;
#pragma unroll
    for (int k = 0; k < CH; ++k) {
        out[k * NPIX + pix] = acc[k];
    }
}

extern "C" void kernel_launch(void* const* d_in, const int* in_sizes, int n_in,
                              void* d_out, int out_size, void* d_ws, size_t ws_size,
                              hipStream_t stream) {
    const float* data = (const float*)d_in[0];     // (4,2,128,2048) f32
    const int* sxy = (const int*)d_in[1];          // (128,2) i32
    float* out = (float*)d_out;                    // (4,2,512,512) f32
    unsigned short* tab = (unsigned short*)d_ws;   // 512*512 u16 = 512 KB

    build_table<<<NPIX / 256, 256, 0, stream>>>(tab);
    das_main<<<1024, 256, 0, stream>>>(data, tab, sxy, out);
}

// Round 6
// 126.621 us; speedup vs baseline: 1.3958x; 1.3958x over previous
//
#include <hip/hip_runtime.h>
#include <math.h>

// DAS beamforming: out[b][c][p] = sum_s data[b][c][s][t(s,p)]
// r5 passed bit-exact (absmax 0.0) with the XLA reciprocal-multiply table chain.
// r5 counters: das_main 125us, occupancy 33% (grid-capped: 4096 waves vs 8192
// slots), VALUBusy 20%, HBM 3% -> latency-bound gather.
// r6: (a) one-time transpose to (s,t,ch) so 8 scattered gathers -> 1 dwordx4;
//     (b) split 8 ch into 2 groups of 4 (gridDim.y=2) -> 8192 waves = 100% slots.

#define NXY 512
#define S_CNT 128
#define T_CNT 2048
#define CH 8                       // B*2 = 4*2
#define CH_STRIDE (S_CNT * T_CNT)  // 262144 floats between channels (orig layout)
#define NPIX (NXY * NXY)
#define TAB_BYTES (NPIX * 2)       // 512 KB u16 table

#pragma float_control(push)
#pragma float_control(precise, on)
__global__ __launch_bounds__(256) void build_table(unsigned short* __restrict__ tab) {
    int idx = blockIdx.x * 256 + threadIdx.x;  // 0 .. 262143
    int adx = idx >> 9;                        // |dx| 0..511
    int ady = idx & 511;                       // |dy| 0..511

    const double DX32 = (double)1e-4f;              // f32 constant, widened exactly
    const double R1 = (double)(float)(1.0 / 1550.0);            // CR f32 recip
    const double R2 = (double)(float)(1.0 / (double)2.5e-8f);   // = 4.0e7 exactly

    float dxf = (float)((double)adx * DX32);        // exact f64 product -> f32 round
    float dyf = (float)((double)ady * DX32);
    float a2 = (float)((double)dxf * (double)dxf);  // exact in f64 -> f32 round
    float b2 = (float)((double)dyf * (double)dyf);
    float sum = (float)((double)a2 + (double)b2);   // exact in f64 -> f32 round
    float dis = (float)sqrt((double)sum);           // CR f32 sqrt via Figueroa
    float q1 = (float)((double)dis * R1);           // CR f32 mul
    float q2 = (float)((double)q1 * R2);            // CR f32 mul
    tab[idx] = (unsigned short)(int)q2;             // trunc = convert<s32>; max 1864
}
#pragma float_control(pop)

// (8ch, 128s, 2048t) -> (128s, 2048t, 8ch). Reads coalesced per channel,
// writes 32 B/thread contiguous. 16 MB total traffic.
__global__ __launch_bounds__(256) void transpose_data(const float* __restrict__ data,
                                                      float* __restrict__ d2) {
    int idx = blockIdx.x * 256 + threadIdx.x;  // s*2048 + t
    float v[CH];
#pragma unroll
    for (int k = 0; k < CH; ++k) v[k] = data[k * CH_STRIDE + idx];
    float4* dst = (float4*)(d2 + (size_t)idx * CH);
    dst[0] = make_float4(v[0], v[1], v[2], v[3]);
    dst[1] = make_float4(v[4], v[5], v[6], v[7]);
}

// Main gather: block = 16x16 pixel tile, wave = 16(iy) x 4(ix) -> t-spread ~50.
// blockIdx.y = channel group (0/1): one float4 gather per (pixel, s).
__global__ __launch_bounds__(256, 8) void das_gather4(const float* __restrict__ d2,
                                                      const unsigned short* __restrict__ tab,
                                                      const int* __restrict__ sxy,
                                                      float* __restrict__ out) {
    __shared__ int sx[S_CNT];
    __shared__ int sy[S_CNT];
    int tid = threadIdx.x;
    if (tid < S_CNT) {
        sx[tid] = sxy[2 * tid];
        sy[tid] = sxy[2 * tid + 1];
    }
    __syncthreads();

    int iy = ((blockIdx.x & 31) << 4) | (tid & 15);
    int ix = ((blockIdx.x >> 5) << 4) | (tid >> 4);
    int g = blockIdx.y;  // channels 4g .. 4g+3

    float4 acc = make_float4(0.f, 0.f, 0.f, 0.f);
#pragma unroll 4
    for (int s = 0; s < S_CNT; ++s) {
        int dxi = sx[s] - ix;
        int dyi = sy[s] - iy;
        int adx = dxi < 0 ? -dxi : dxi;
        int ady = dyi < 0 ? -dyi : dyi;
        int t = (int)tab[(adx << 9) | ady];
        const float4* p = (const float4*)(d2 + (size_t)(((s << 11) + t) << 3)) + g;
        float4 v = *p;
        acc.x += v.x;  // s-ascending per channel: bit-exact vs reference scan
        acc.y += v.y;
        acc.z += v.z;
        acc.w += v.w;
    }

    int pix = (ix << 9) | iy;
    float* o = out + (size_t)(g * 4) * NPIX + pix;
    o[0] = acc.x;
    o[NPIX] = acc.y;
    o[2 * NPIX] = acc.z;
    o[3 * NPIX] = acc.w;
}

// r5 fallback (used only if ws_size can't hold table + transposed data).
__global__ __launch_bounds__(256) void das_main(const float* __restrict__ data,
                                                const unsigned short* __restrict__ tab,
                                                const int* __restrict__ sxy,
                                                float* __restrict__ out) {
    __shared__ int sx[S_CNT];
    __shared__ int sy[S_CNT];
    int tid = threadIdx.x;
    if (tid < S_CNT) {
        sx[tid] = sxy[2 * tid];
        sy[tid] = sxy[2 * tid + 1];
    }
    __syncthreads();
    int iy = ((blockIdx.x & 31) << 4) | (tid & 15);
    int ix = ((blockIdx.x >> 5) << 4) | (tid >> 4);
    float acc[CH];
#pragma unroll
    for (int k = 0; k < CH; ++k) acc[k] = 0.0f;
#pragma unroll 4
    for (int s = 0; s < S_CNT; ++s) {
        int dxi = sx[s] - ix;
        int dyi = sy[s] - iy;
        int adx = dxi < 0 ? -dxi : dxi;
        int ady = dyi < 0 ? -dyi : dyi;
        int t = (int)tab[(adx << 9) | ady];
        const float* p = data + (s << 11) + t;
#pragma unroll
        for (int k = 0; k < CH; ++k) acc[k] += p[(size_t)k * CH_STRIDE];
    }
    int pix = (ix << 9) | iy;
#pragma unroll
    for (int k = 0; k < CH; ++k) out[k * NPIX + pix] = acc[k];
}

extern "C" void kernel_launch(void* const* d_in, const int* in_sizes, int n_in,
                              void* d_out, int out_size, void* d_ws, size_t ws_size,
                              hipStream_t stream) {
    const float* data = (const float*)d_in[0];     // (4,2,128,2048) f32
    const int* sxy = (const int*)d_in[1];          // (128,2) i32
    float* out = (float*)d_out;                    // (4,2,512,512) f32
    unsigned short* tab = (unsigned short*)d_ws;   // 512 KB

    build_table<<<NPIX / 256, 256, 0, stream>>>(tab);

    size_t need = (size_t)TAB_BYTES + (size_t)CH_STRIDE * CH * sizeof(float);  // 8.5 MB
    if (ws_size >= need) {
        float* d2 = (float*)((char*)d_ws + TAB_BYTES);
        transpose_data<<<CH_STRIDE / 256, 256, 0, stream>>>(data, d2);
        das_gather4<<<dim3(1024, 2), 256, 0, stream>>>(d2, tab, sxy, out);
    } else {
        das_main<<<1024, 256, 0, stream>>>(data, tab, sxy, out);
    }
}

// Round 8
// 119.434 us; speedup vs baseline: 1.4797x; 1.0602x over previous
//
#include <hip/hip_runtime.h>
#include <math.h>

// DAS beamforming: out[b][c][p] = sum_s data[b][c][s][t(s,p)]
// Table chain: ONLY the f64-emulated chain is proven bit-exact (r5/r6 absmax
// 0.0). r7's native-f32 version regressed (absmax 3.56; likely harness-level
// -ffp-contract=fast fusing dx*dx+b2, or non-CR sqrt). DO NOT substitute
// native f32 for the table math.
//   dx=f32(adx*f64(1e-4f)); a2=f32(dx*dx); sum=f32(a2+b2); dis=f32(sqrt_f64(sum));
//   q=f32(f32(dis*R1)*R2), R1=f32(1/1550.0), R2=f32(1/f32(2.5e-8))=4e7 exactly.
// Runtime ops are f64 mul/sqrt only (reciprocals are compile-time consts).
// r8: fuse table build into transpose (prep); gather = 1 thread x 8 channels
// (das_gather8, halves L1 line-services vs r6's 2 channel-groups), 8x8 wave tile.

#define NXY 512
#define S_CNT 128
#define T_CNT 2048
#define CH 8                       // B*2 = 4*2
#define CH_STRIDE (S_CNT * T_CNT)  // 262144 floats between channels (orig layout)
#define NPIX (NXY * NXY)
#define TAB_BYTES (NPIX * 2)       // 512 KB u16 table

#pragma float_control(push)
#pragma float_control(precise, on)
__device__ __forceinline__ unsigned short delay_entry(int adx, int ady) {
    const double DX32 = (double)1e-4f;                        // f32 const, exact widen
    const double R1 = (double)(float)(1.0 / 1550.0);          // CR f32 reciprocal
    const double R2 = (double)(float)(1.0 / (double)2.5e-8f); // = 4.0e7 exactly
    float dxf = (float)((double)adx * DX32);        // exact f64 product -> f32 round
    float dyf = (float)((double)ady * DX32);
    float a2 = (float)((double)dxf * (double)dxf);  // exact in f64 -> f32 round
    float b2 = (float)((double)dyf * (double)dyf);
    float sum = (float)((double)a2 + (double)b2);   // exact in f64 -> f32 round
    float dis = (float)sqrt((double)sum);           // CR f32 sqrt via Figueroa
    float q1 = (float)((double)dis * R1);           // CR f32 mul (exact f64 product)
    float q2 = (float)((double)q1 * R2);            // CR f32 mul (exact f64 product)
    return (unsigned short)(int)q2;                 // trunc = convert<s32>; max 1864
}

// Fused: table entry idx + transpose (8ch,128s,2048t) -> (128s,2048t,8ch).
__global__ __launch_bounds__(256) void prep(const float* __restrict__ data,
                                            unsigned short* __restrict__ tab,
                                            float* __restrict__ d2) {
    int idx = blockIdx.x * 256 + threadIdx.x;  // 0 .. 262143 (NPIX == 128*2048)
    tab[idx] = delay_entry(idx >> 9, idx & 511);

    float v[CH];
#pragma unroll
    for (int k = 0; k < CH; ++k) v[k] = data[k * CH_STRIDE + idx];
    float4* dst = (float4*)(d2 + (size_t)idx * CH);
    dst[0] = make_float4(v[0], v[1], v[2], v[3]);
    dst[1] = make_float4(v[4], v[5], v[6], v[7]);
}
#pragma float_control(pop)

// Gather: 1 thread = 1 pixel x all 8 channels (two dwordx4 from one 32B chunk).
// Wave = 8x8 pixel tile (t-spread ~36 worst-case). Block = 16x16 px (4 waves).
__global__ __launch_bounds__(256) void das_gather8(const float* __restrict__ d2,
                                                   const unsigned short* __restrict__ tab,
                                                   const int* __restrict__ sxy,
                                                   float* __restrict__ out) {
    __shared__ int sx[S_CNT];
    __shared__ int sy[S_CNT];
    int tid = threadIdx.x;
    if (tid < S_CNT) {
        sx[tid] = sxy[2 * tid];
        sy[tid] = sxy[2 * tid + 1];
    }
    __syncthreads();

    // lane bits: iy[2:0]=tid[2:0], ix[2:0]=tid[5:3]; wave bits: iy[3]=tid[6], ix[3]=tid[7]
    int iy = ((blockIdx.x & 31) << 4) | (((tid >> 6) & 1) << 3) | (tid & 7);
    int ix = ((blockIdx.x >> 5) << 4) | ((tid >> 7) << 3) | ((tid >> 3) & 7);

    float4 acc0 = make_float4(0.f, 0.f, 0.f, 0.f);
    float4 acc1 = make_float4(0.f, 0.f, 0.f, 0.f);

#pragma unroll 4
    for (int s = 0; s < S_CNT; ++s) {
        int dxi = sx[s] - ix;
        int dyi = sy[s] - iy;
        int adx = dxi < 0 ? -dxi : dxi;
        int ady = dyi < 0 ? -dyi : dyi;
        int t = (int)tab[(adx << 9) | ady];
        const float4* p = (const float4*)d2 + (((s << 11) + t) << 1);
        float4 v0 = p[0];
        float4 v1 = p[1];
        acc0.x += v0.x;  // per-channel s-ascending: bit-exact vs reference scan
        acc0.y += v0.y;
        acc0.z += v0.z;
        acc0.w += v0.w;
        acc1.x += v1.x;
        acc1.y += v1.y;
        acc1.z += v1.z;
        acc1.w += v1.w;
    }

    int pix = (ix << 9) | iy;
    out[0 * NPIX + pix] = acc0.x;
    out[1 * NPIX + pix] = acc0.y;
    out[2 * NPIX + pix] = acc0.z;
    out[3 * NPIX + pix] = acc0.w;
    out[4 * NPIX + pix] = acc1.x;
    out[5 * NPIX + pix] = acc1.y;
    out[6 * NPIX + pix] = acc1.z;
    out[7 * NPIX + pix] = acc1.w;
}

// ---------- fallback path (ws too small): r5-proven build_table + das_main ----------
#pragma float_control(push)
#pragma float_control(precise, on)
__global__ __launch_bounds__(256) void build_table(unsigned short* __restrict__ tab) {
    int idx = blockIdx.x * 256 + threadIdx.x;
    tab[idx] = delay_entry(idx >> 9, idx & 511);
}
#pragma float_control(pop)

__global__ __launch_bounds__(256) void das_main(const float* __restrict__ data,
                                                const unsigned short* __restrict__ tab,
                                                const int* __restrict__ sxy,
                                                float* __restrict__ out) {
    __shared__ int sx[S_CNT];
    __shared__ int sy[S_CNT];
    int tid = threadIdx.x;
    if (tid < S_CNT) {
        sx[tid] = sxy[2 * tid];
        sy[tid] = sxy[2 * tid + 1];
    }
    __syncthreads();
    int iy = ((blockIdx.x & 31) << 4) | (tid & 15);
    int ix = ((blockIdx.x >> 5) << 4) | (tid >> 4);
    float acc[CH];
#pragma unroll
    for (int k = 0; k < CH; ++k) acc[k] = 0.0f;
#pragma unroll 4
    for (int s = 0; s < S_CNT; ++s) {
        int dxi = sx[s] - ix;
        int dyi = sy[s] - iy;
        int adx = dxi < 0 ? -dxi : dxi;
        int ady = dyi < 0 ? -dyi : dyi;
        int t = (int)tab[(adx << 9) | ady];
        const float* p = data + (s << 11) + t;
#pragma unroll
        for (int k = 0; k < CH; ++k) acc[k] += p[(size_t)k * CH_STRIDE];
    }
    int pix = (ix << 9) | iy;
#pragma unroll
    for (int k = 0; k < CH; ++k) out[k * NPIX + pix] = acc[k];
}

extern "C" void kernel_launch(void* const* d_in, const int* in_sizes, int n_in,
                              void* d_out, int out_size, void* d_ws, size_t ws_size,
                              hipStream_t stream) {
    const float* data = (const float*)d_in[0];     // (4,2,128,2048) f32
    const int* sxy = (const int*)d_in[1];          // (128,2) i32
    float* out = (float*)d_out;                    // (4,2,512,512) f32
    unsigned short* tab = (unsigned short*)d_ws;   // 512 KB

    size_t need = (size_t)TAB_BYTES + (size_t)CH_STRIDE * CH * sizeof(float);  // 8.5 MB
    if (ws_size >= need) {
        float* d2 = (float*)((char*)d_ws + TAB_BYTES);
        prep<<<NPIX / 256, 256, 0, stream>>>(data, tab, d2);
        das_gather8<<<1024, 256, 0, stream>>>(d2, tab, sxy, out);
    } else {
        build_table<<<NPIX / 256, 256, 0, stream>>>(tab);
        das_main<<<1024, 256, 0, stream>>>(data, tab, sxy, out);
    }
}